// Round 1
// baseline (1128.122 us; speedup 1.0000x reference)
//
#include <hip/hip_runtime.h>
#include <math.h>

// VQVAE forward, MI355X. Round 1: all-fp32 correctness baseline.
// Pipeline: h1=relu(x@W1^T+b1); z_e=h1@W2^T+b2; idx=argmin_j ||z_e-e_j||^2;
//           h3=relu(emb[idx]@W3^T+b3); out=sigmoid(h3@W4^T+b4)
// argmin uses dist'[i,j] = ||e_j||^2 - 2 z_e_i . e_j  (row-constant ||z_e||^2 dropped)

#define TILE_M 64
#define TILE_N 64
#define TILE_K 16

enum { ACT_NONE = 0, ACT_RELU = 1, ACT_SIGMOID = 2 };

// C[M,N] = act(A[M,K] @ B[N,K]^T + bias)   (A optionally row-indirected via aidx)
// Requirements: M % 64 == 0, K % 16 == 0, N % 4 == 0 (guards handle N % 64 != 0)
template <int ACT, bool INDIRECT>
__global__ __launch_bounds__(256) void gemm_nt(
    const float* __restrict__ A, const float* __restrict__ B,
    const float* __restrict__ bias, float* __restrict__ C,
    int M, int N, int K, const int* __restrict__ aidx) {
  __shared__ float As[TILE_K][TILE_M + 1];
  __shared__ float Bs[TILE_K][TILE_N + 1];
  const int tid = threadIdx.x;
  const int ty = tid >> 4;   // 0..15
  const int tx = tid & 15;   // 0..15
  const int row0 = blockIdx.y * TILE_M;
  const int col0 = blockIdx.x * TILE_N;

  const int lrow = tid >> 2;         // 0..63
  const int lk = (tid & 3) << 2;     // 0,4,8,12

  long asrc = INDIRECT ? (long)aidx[row0 + lrow] : (long)(row0 + lrow);
  const float* aptr = A + asrc * K + lk;
  const int bn = col0 + lrow;
  const float* bptr = B + (long)bn * K + lk;
  const bool bvalid = (bn < N);

  float acc[4][4];
#pragma unroll
  for (int i = 0; i < 4; i++)
#pragma unroll
    for (int j = 0; j < 4; j++) acc[i][j] = 0.f;

  for (int k0 = 0; k0 < K; k0 += TILE_K) {
    float4 av = *(const float4*)(aptr + k0);
    float4 bv = bvalid ? *(const float4*)(bptr + k0) : float4{0.f, 0.f, 0.f, 0.f};
    __syncthreads();
    As[lk + 0][lrow] = av.x; As[lk + 1][lrow] = av.y;
    As[lk + 2][lrow] = av.z; As[lk + 3][lrow] = av.w;
    Bs[lk + 0][lrow] = bv.x; Bs[lk + 1][lrow] = bv.y;
    Bs[lk + 2][lrow] = bv.z; Bs[lk + 3][lrow] = bv.w;
    __syncthreads();
#pragma unroll
    for (int kk = 0; kk < TILE_K; kk++) {
      float4 a = *(const float4*)&As[kk][ty << 2];
      float4 b = *(const float4*)&Bs[kk][tx << 2];
      acc[0][0] = fmaf(a.x, b.x, acc[0][0]);
      acc[0][1] = fmaf(a.x, b.y, acc[0][1]);
      acc[0][2] = fmaf(a.x, b.z, acc[0][2]);
      acc[0][3] = fmaf(a.x, b.w, acc[0][3]);
      acc[1][0] = fmaf(a.y, b.x, acc[1][0]);
      acc[1][1] = fmaf(a.y, b.y, acc[1][1]);
      acc[1][2] = fmaf(a.y, b.z, acc[1][2]);
      acc[1][3] = fmaf(a.y, b.w, acc[1][3]);
      acc[2][0] = fmaf(a.z, b.x, acc[2][0]);
      acc[2][1] = fmaf(a.z, b.y, acc[2][1]);
      acc[2][2] = fmaf(a.z, b.z, acc[2][2]);
      acc[2][3] = fmaf(a.z, b.w, acc[2][3]);
      acc[3][0] = fmaf(a.w, b.x, acc[3][0]);
      acc[3][1] = fmaf(a.w, b.y, acc[3][1]);
      acc[3][2] = fmaf(a.w, b.z, acc[3][2]);
      acc[3][3] = fmaf(a.w, b.w, acc[3][3]);
    }
  }

  const int c = col0 + (tx << 2);
  if (c < N) {  // N%4==0 so the whole float4 is in-bounds when c < N
    float4 bb = *(const float4*)(bias + c);
#pragma unroll
    for (int i = 0; i < 4; i++) {
      const int r = row0 + (ty << 2) + i;
      float4 v;
      v.x = acc[i][0] + bb.x;
      v.y = acc[i][1] + bb.y;
      v.z = acc[i][2] + bb.z;
      v.w = acc[i][3] + bb.w;
      if (ACT == ACT_RELU) {
        v.x = fmaxf(v.x, 0.f); v.y = fmaxf(v.y, 0.f);
        v.z = fmaxf(v.z, 0.f); v.w = fmaxf(v.w, 0.f);
      } else if (ACT == ACT_SIGMOID) {
        v.x = 1.f / (1.f + expf(-v.x));
        v.y = 1.f / (1.f + expf(-v.y));
        v.z = 1.f / (1.f + expf(-v.z));
        v.w = 1.f / (1.f + expf(-v.w));
      }
      *(float4*)(C + (long)r * N + c) = v;
    }
  }
}

// ||emb_j||^2, one wave per codebook row (D=256 -> 64 lanes x float4)
__global__ __launch_bounds__(256) void emb_norm(const float* __restrict__ emb,
                                                float* __restrict__ enorm) {
  const int gtid = blockIdx.x * 256 + threadIdx.x;
  const int j = gtid >> 6;
  const int lane = threadIdx.x & 63;
  float4 v = *(const float4*)(emb + (long)j * 256 + (lane << 2));
  float s = v.x * v.x + v.y * v.y + v.z * v.z + v.w * v.w;
#pragma unroll
  for (int off = 1; off < 64; off <<= 1) s += __shfl_xor(s, off, 64);
  if (lane == 0) enorm[j] = s;
}

// Partial argmin over a 64-row x 64-col tile of dist'[i,j] = enorm[j] - 2 z.e_j
// K = 256, N = 2048 fixed. Writes (val,idx) per (colchunk,row).
__global__ __launch_bounds__(256) void dist_partial(
    const float* __restrict__ Z, const float* __restrict__ E,
    const float* __restrict__ enorm, float* __restrict__ pval,
    int* __restrict__ pidx, int M) {
  const int K = 256;
  __shared__ float As[TILE_K][TILE_M + 1];
  __shared__ float Bs[TILE_K][TILE_N + 1];
  const int tid = threadIdx.x;
  const int ty = tid >> 4;
  const int tx = tid & 15;
  const int row0 = blockIdx.y * TILE_M;
  const int col0 = blockIdx.x * TILE_N;
  const int lrow = tid >> 2;
  const int lk = (tid & 3) << 2;

  const float* aptr = Z + (long)(row0 + lrow) * K + lk;
  const float* bptr = E + (long)(col0 + lrow) * K + lk;

  float acc[4][4];
#pragma unroll
  for (int i = 0; i < 4; i++)
#pragma unroll
    for (int j = 0; j < 4; j++) acc[i][j] = 0.f;

  for (int k0 = 0; k0 < K; k0 += TILE_K) {
    float4 av = *(const float4*)(aptr + k0);
    float4 bv = *(const float4*)(bptr + k0);
    __syncthreads();
    As[lk + 0][lrow] = av.x; As[lk + 1][lrow] = av.y;
    As[lk + 2][lrow] = av.z; As[lk + 3][lrow] = av.w;
    Bs[lk + 0][lrow] = bv.x; Bs[lk + 1][lrow] = bv.y;
    Bs[lk + 2][lrow] = bv.z; Bs[lk + 3][lrow] = bv.w;
    __syncthreads();
#pragma unroll
    for (int kk = 0; kk < TILE_K; kk++) {
      float4 a = *(const float4*)&As[kk][ty << 2];
      float4 b = *(const float4*)&Bs[kk][tx << 2];
      acc[0][0] = fmaf(a.x, b.x, acc[0][0]);
      acc[0][1] = fmaf(a.x, b.y, acc[0][1]);
      acc[0][2] = fmaf(a.x, b.z, acc[0][2]);
      acc[0][3] = fmaf(a.x, b.w, acc[0][3]);
      acc[1][0] = fmaf(a.y, b.x, acc[1][0]);
      acc[1][1] = fmaf(a.y, b.y, acc[1][1]);
      acc[1][2] = fmaf(a.y, b.z, acc[1][2]);
      acc[1][3] = fmaf(a.y, b.w, acc[1][3]);
      acc[2][0] = fmaf(a.z, b.x, acc[2][0]);
      acc[2][1] = fmaf(a.z, b.y, acc[2][1]);
      acc[2][2] = fmaf(a.z, b.z, acc[2][2]);
      acc[2][3] = fmaf(a.z, b.w, acc[2][3]);
      acc[3][0] = fmaf(a.w, b.x, acc[3][0]);
      acc[3][1] = fmaf(a.w, b.y, acc[3][1]);
      acc[3][2] = fmaf(a.w, b.z, acc[3][2]);
      acc[3][3] = fmaf(a.w, b.w, acc[3][3]);
    }
  }

  const int c = col0 + (tx << 2);
  float4 en = *(const float4*)(enorm + c);
#pragma unroll
  for (int i = 0; i < 4; i++) {
    float v0 = en.x - 2.f * acc[i][0];
    float v1 = en.y - 2.f * acc[i][1];
    float v2 = en.z - 2.f * acc[i][2];
    float v3 = en.w - 2.f * acc[i][3];
    float bv = v0; int bj = c;
    if (v1 < bv) { bv = v1; bj = c + 1; }
    if (v2 < bv) { bv = v2; bj = c + 2; }
    if (v3 < bv) { bv = v3; bj = c + 3; }
    // reduce across the 16 tx lanes (contiguous within the wave)
#pragma unroll
    for (int off = 1; off < 16; off <<= 1) {
      float ov = __shfl_xor(bv, off, 64);
      int oj = __shfl_xor(bj, off, 64);
      if (ov < bv || (ov == bv && oj < bj)) { bv = ov; bj = oj; }
    }
    if (tx == 0) {
      const int r = row0 + (ty << 2) + i;
      pval[(long)blockIdx.x * M + r] = bv;
      pidx[(long)blockIdx.x * M + r] = bj;
    }
  }
}

__global__ __launch_bounds__(256) void argmin_final(
    const float* __restrict__ pval, const int* __restrict__ pidx,
    int* __restrict__ idx, int M, int nch) {
  const int r = blockIdx.x * 256 + threadIdx.x;
  if (r >= M) return;
  float best = pval[r];
  int bi = pidx[r];
  for (int c = 1; c < nch; c++) {
    float v = pval[(long)c * M + r];
    int i = pidx[(long)c * M + r];
    if (v < best || (v == best && i < bi)) { best = v; bi = i; }
  }
  idx[r] = bi;
}

extern "C" void kernel_launch(void* const* d_in, const int* in_sizes, int n_in,
                              void* d_out, int out_size, void* d_ws, size_t ws_size,
                              hipStream_t stream) {
  const float* x   = (const float*)d_in[0];
  const float* W1  = (const float*)d_in[1];
  const float* b1  = (const float*)d_in[2];
  const float* W2  = (const float*)d_in[3];
  const float* b2  = (const float*)d_in[4];
  const float* W3  = (const float*)d_in[5];
  const float* b3  = (const float*)d_in[6];
  const float* W4  = (const float*)d_in[7];
  const float* b4  = (const float*)d_in[8];
  const float* emb = (const float*)d_in[9];
  float* out = (float*)d_out;

  const int BZ = 16384, IN = 1024, H = 400, D = 256, NE = 2048;

  char* ws = (char*)d_ws;
  float* h1    = (float*)(ws);                               // 16384*400
  float* z_e   = (float*)(ws + 26214400);                    // 16384*256
  float* h3    = (float*)(ws + 26214400 + 16777216);         // 16384*400
  float* enorm = (float*)(ws + 69206016);                    // 2048
  float* pval  = (float*)(ws + 69214208);                    // 16384*32
  int*   pidx  = (int*)  (ws + 71311360);                    // 16384*32
  int*   idx   = (int*)  (ws + 73408512);                    // 16384

  // 0: codebook norms
  emb_norm<<<dim3(NE * 64 / 256), dim3(256), 0, stream>>>(emb, enorm);

  // 1: h1 = relu(x @ W1^T + b1)   (16384 x 400, K=1024)
  gemm_nt<ACT_RELU, false><<<dim3((H + TILE_N - 1) / TILE_N, BZ / TILE_M),
                             dim3(256), 0, stream>>>(x, W1, b1, h1, BZ, H, IN, nullptr);

  // 2: z_e = h1 @ W2^T + b2       (16384 x 256, K=400)
  gemm_nt<ACT_NONE, false><<<dim3(D / TILE_N, BZ / TILE_M),
                             dim3(256), 0, stream>>>(h1, W2, b2, z_e, BZ, D, H, nullptr);

  // 3: chunked argmin over dist'(i,j)
  dist_partial<<<dim3(NE / TILE_N, BZ / TILE_M), dim3(256), 0, stream>>>(
      z_e, emb, enorm, pval, pidx, BZ);
  argmin_final<<<dim3(BZ / 256), dim3(256), 0, stream>>>(pval, pidx, idx, BZ, NE / TILE_N);

  // 4: h3 = relu(emb[idx] @ W3^T + b3)  (16384 x 400, K=256) — gather fused
  gemm_nt<ACT_RELU, true><<<dim3((H + TILE_N - 1) / TILE_N, BZ / TILE_M),
                            dim3(256), 0, stream>>>(emb, W3, b3, h3, BZ, H, D, idx);

  // 5: out = sigmoid(h3 @ W4^T + b4)    (16384 x 1024, K=400)
  gemm_nt<ACT_SIGMOID, false><<<dim3(IN / TILE_N, BZ / TILE_M),
                                dim3(256), 0, stream>>>(h3, W4, b4, out, BZ, IN, H, nullptr);
}

// Round 2
// 715.518 us; speedup vs baseline: 1.5767x; 1.5767x over previous
//
#include <hip/hip_runtime.h>
#include <math.h>
#include <float.h>

// VQVAE forward, MI355X. Round 2: bf16x3 (hi/mid split) MFMA GEMMs everywhere.
// dist argmin: bf16x3 MFMA top-2-per-128-chunk candidates + exact fp32 rescore.
// H padded 400->512 with zero weights (inert through relu / K-dim zeros).

typedef __attribute__((ext_vector_type(8))) short short8;      // MFMA A/B frag (8 bf16)
typedef __attribute__((ext_vector_type(4))) float floatx4;     // MFMA C/D frag
typedef __attribute__((ext_vector_type(4))) unsigned short ushort4v;
typedef __attribute__((ext_vector_type(8))) unsigned short ushort8v;

__device__ __forceinline__ unsigned short f2bf(float f) {
  union { float f; unsigned u; } v; v.f = f;
  unsigned u = v.u;
  return (unsigned short)((u + 0x7FFFu + ((u >> 16) & 1u)) >> 16);
}
__device__ __forceinline__ float bf2f(unsigned short s) {
  union { unsigned u; float f; } v; v.u = ((unsigned)s) << 16;
  return v.f;
}

// fp32 [R][C] -> zero-padded bf16 hi/mid [Rp][Cp]
__global__ __launch_bounds__(256) void conv_pad(
    const float* __restrict__ src, unsigned short* __restrict__ hi,
    unsigned short* __restrict__ mid, int R, int C, int Rp, int Cp) {
  int t = blockIdx.x * 256 + threadIdx.x;
  if (t >= Rp * Cp) return;
  int r = t / Cp, c = t - r * Cp;
  float v = (r < R && c < C) ? src[(long)r * C + c] : 0.f;
  unsigned short h = f2bf(v);
  hi[t] = h;
  mid[t] = f2bf(v - bf2f(h));
}

// ||emb_j||^2 fp32, one wave per codebook row
__global__ __launch_bounds__(256) void emb_norm(const float* __restrict__ emb,
                                                float* __restrict__ enorm) {
  const int gtid = blockIdx.x * 256 + threadIdx.x;
  const int j = gtid >> 6;
  const int lane = threadIdx.x & 63;
  float4 v = *(const float4*)(emb + (long)j * 256 + (lane << 2));
  float s = v.x * v.x + v.y * v.y + v.z * v.z + v.w * v.w;
#pragma unroll
  for (int off = 1; off < 64; off <<= 1) s += __shfl_xor(s, off, 64);
  if (lane == 0) enorm[j] = s;
}

__device__ __forceinline__ void ins_top2(float d, int j, float& v1, int& i1,
                                         float& v2, int& i2) {
  if (d < v1 || (d == v1 && j < i1)) {
    v2 = v1; i2 = i1; v1 = d; i1 = j;
  } else if (d < v2 || (d == v2 && j < i2)) {
    v2 = d; i2 = j;
  }
}

#define BM 128
#define BN 128
#define BK 32
#define LDK 40  // lds row pitch in shorts (80B = 20 banks -> max 2-way, free)

enum { EPI_NONE = 0, EPI_RELU = 1, EPI_SIGMOID = 2, EPI_DIST = 3 };

// C[M,N] = epi(A_f32[M,K] @ (Bhi+Bmid)[N,K]^T + bias)
// bf16x3: a_hi*b_hi + a_hi*b_mid + a_mid*b_hi. A converted fp32->hi/mid in staging.
// M%128==0, N%128==0, K%32==0 (pre-padded).
template <int EPI, bool INDIRECT>
__global__ __launch_bounds__(256, 2) void mfma_gemm(
    const float* __restrict__ A, const unsigned short* __restrict__ Bhi,
    const unsigned short* __restrict__ Bmid, const float* __restrict__ bias,
    float* __restrict__ Cf, const int* __restrict__ aidx,
    const float* __restrict__ enorm, int* __restrict__ pidx,
    int M, int N, int K, int Nreal) {
  __shared__ unsigned short Ah[BM][LDK], Am[BM][LDK];
  __shared__ unsigned short Bh[BN][LDK], Bm[BN][LDK];
  __shared__ int idxs[BM];

  const int tid = threadIdx.x;
  const int lane = tid & 63;
  const int wave = tid >> 6;
  const int wm = wave >> 1, wn = wave & 1;  // 2x2 waves, 64x64 tiles
  const int row0 = blockIdx.y * BM, col0 = blockIdx.x * BN;

  if (INDIRECT) {
    if (tid < BM) idxs[tid] = aidx[row0 + tid];
    __syncthreads();
  }

  // A staging: 4 cells/thread of float4; cell i -> row i*32+(tid>>3), f4col tid&7
  const float* aRow[4];
#pragma unroll
  for (int i = 0; i < 4; i++) {
    int r = i * 32 + (tid >> 3);
    long ar = INDIRECT ? (long)idxs[r] : (long)(row0 + r);
    aRow[i] = A + ar * K + (tid & 7) * 4;
  }
  // B staging: 2 cells/thread of ushort8 per array; cell i -> row i*64+(tid>>2), q tid&3
  const unsigned short* bRowH[2];
  const unsigned short* bRowM[2];
#pragma unroll
  for (int i = 0; i < 2; i++) {
    int r = col0 + i * 64 + (tid >> 2);
    bRowH[i] = Bhi + (long)r * K + (tid & 3) * 8;
    bRowM[i] = Bmid + (long)r * K + (tid & 3) * 8;
  }

  floatx4 acc[4][4];
#pragma unroll
  for (int i = 0; i < 4; i++)
#pragma unroll
    for (int j = 0; j < 4; j++) acc[i][j] = (floatx4)0.f;

  for (int k0 = 0; k0 < K; k0 += BK) {
    float4 areg[4];
    ushort8v bh_reg[2], bm_reg[2];
#pragma unroll
    for (int i = 0; i < 4; i++) areg[i] = *(const float4*)(aRow[i] + k0);
#pragma unroll
    for (int i = 0; i < 2; i++) {
      bh_reg[i] = *(const ushort8v*)(bRowH[i] + k0);
      bm_reg[i] = *(const ushort8v*)(bRowM[i] + k0);
    }
    __syncthreads();
#pragma unroll
    for (int i = 0; i < 4; i++) {
      int r = i * 32 + (tid >> 3), q4 = (tid & 7) * 4;
      ushort4v h, m;
      h.x = f2bf(areg[i].x); m.x = f2bf(areg[i].x - bf2f(h.x));
      h.y = f2bf(areg[i].y); m.y = f2bf(areg[i].y - bf2f(h.y));
      h.z = f2bf(areg[i].z); m.z = f2bf(areg[i].z - bf2f(h.z));
      h.w = f2bf(areg[i].w); m.w = f2bf(areg[i].w - bf2f(h.w));
      *(ushort4v*)&Ah[r][q4] = h;
      *(ushort4v*)&Am[r][q4] = m;
    }
#pragma unroll
    for (int i = 0; i < 2; i++) {
      int r = i * 64 + (tid >> 2), q8 = (tid & 3) * 8;
      *(ushort8v*)&Bh[r][q8] = bh_reg[i];
      *(ushort8v*)&Bm[r][q8] = bm_reg[i];
    }
    __syncthreads();

    short8 ah[4], am[4];
#pragma unroll
    for (int tm = 0; tm < 4; tm++) {
      const int rr = wm * 64 + tm * 16 + (lane & 15);
      const int kk = (lane >> 4) * 8;
      ah[tm] = *(const short8*)&Ah[rr][kk];
      am[tm] = *(const short8*)&Am[rr][kk];
    }
#pragma unroll
    for (int tn = 0; tn < 4; tn++) {
      const int rr = wn * 64 + tn * 16 + (lane & 15);
      const int kk = (lane >> 4) * 8;
      short8 bh = *(const short8*)&Bh[rr][kk];
      short8 bm = *(const short8*)&Bm[rr][kk];
#pragma unroll
      for (int tm = 0; tm < 4; tm++) {
        acc[tm][tn] = __builtin_amdgcn_mfma_f32_16x16x32_bf16(ah[tm], bh, acc[tm][tn], 0, 0, 0);
        acc[tm][tn] = __builtin_amdgcn_mfma_f32_16x16x32_bf16(ah[tm], bm, acc[tm][tn], 0, 0, 0);
        acc[tm][tn] = __builtin_amdgcn_mfma_f32_16x16x32_bf16(am[tm], bh, acc[tm][tn], 0, 0, 0);
      }
    }
  }

  // C/D layout (m89/m91 verified): col = lane&15, row = (lane>>4)*4 + reg
  const int qd = lane >> 4, ln = lane & 15;
  if (EPI != EPI_DIST) {
#pragma unroll
    for (int tn = 0; tn < 4; tn++) {
      const int c = col0 + wn * 64 + tn * 16 + ln;
      const float bb = (c < Nreal) ? bias[c] : 0.f;
#pragma unroll
      for (int tm = 0; tm < 4; tm++) {
#pragma unroll
        for (int reg = 0; reg < 4; reg++) {
          const int r = row0 + wm * 64 + tm * 16 + qd * 4 + reg;
          float v = acc[tm][tn][reg] + bb;
          if (EPI == EPI_RELU) v = fmaxf(v, 0.f);
          if (EPI == EPI_SIGMOID) v = 1.f / (1.f + expf(-v));
          Cf[(long)r * N + c] = v;
        }
      }
    }
  } else {
    // dist epilogue: d = ||e_c||^2 - 2*dot; top-2 per (row, 128-col chunk)
    __shared__ float tv1s[2][BM], tv2s[2][BM];
    __shared__ int ti1s[2][BM], ti2s[2][BM];
    float en[4];
#pragma unroll
    for (int tn = 0; tn < 4; tn++) en[tn] = enorm[col0 + wn * 64 + tn * 16 + ln];
#pragma unroll
    for (int tm = 0; tm < 4; tm++) {
#pragma unroll
      for (int reg = 0; reg < 4; reg++) {
        float v1 = FLT_MAX, v2 = FLT_MAX;
        int i1 = 0x7fffffff, i2 = 0x7fffffff;
#pragma unroll
        for (int tn = 0; tn < 4; tn++) {
          const int c = col0 + wn * 64 + tn * 16 + ln;
          float d = en[tn] - 2.f * acc[tm][tn][reg];
          ins_top2(d, c, v1, i1, v2, i2);
        }
#pragma unroll
        for (int off = 1; off < 16; off <<= 1) {
          float ov1 = __shfl_xor(v1, off, 64);
          int oi1 = __shfl_xor(i1, off, 64);
          float ov2 = __shfl_xor(v2, off, 64);
          int oi2 = __shfl_xor(i2, off, 64);
          ins_top2(ov1, oi1, v1, i1, v2, i2);
          ins_top2(ov2, oi2, v1, i1, v2, i2);
        }
        if (ln == 0) {
          const int rl = wm * 64 + tm * 16 + qd * 4 + reg;
          tv1s[wn][rl] = v1; ti1s[wn][rl] = i1;
          tv2s[wn][rl] = v2; ti2s[wn][rl] = i2;
        }
      }
    }
    __syncthreads();
    if (tid < BM) {
      float v1 = tv1s[0][tid], v2 = tv2s[0][tid];
      int i1 = ti1s[0][tid], i2 = ti2s[0][tid];
      ins_top2(tv1s[1][tid], ti1s[1][tid], v1, i1, v2, i2);
      ins_top2(tv2s[1][tid], ti2s[1][tid], v1, i1, v2, i2);
      const long base = ((long)blockIdx.x * M + (row0 + tid)) * 2;
      pidx[base] = i1;
      pidx[base + 1] = i2;
    }
  }
}

// exact fp32 rescore of 32 candidates/row; one wave per row
__global__ __launch_bounds__(256) void rescore(
    const float* __restrict__ z, const float* __restrict__ emb,
    const float* __restrict__ enorm, const int* __restrict__ pidx,
    int* __restrict__ idx, int M) {
  const int wave = threadIdx.x >> 6, lane = threadIdx.x & 63;
  const int r = blockIdx.x * 4 + wave;
  float4 zv = *(const float4*)(z + (long)r * 256 + lane * 4);
  float best = FLT_MAX;
  int bi = 0x7fffffff;
  for (int c = 0; c < 32; c++) {
    const int j = pidx[((long)(c >> 1) * M + r) * 2 + (c & 1)];
    float4 ev = *(const float4*)(emb + (long)j * 256 + lane * 4);
    float t = zv.x * ev.x + zv.y * ev.y + zv.z * ev.z + zv.w * ev.w;
#pragma unroll
    for (int off = 1; off < 64; off <<= 1) t += __shfl_xor(t, off, 64);
    const float d = enorm[j] - 2.f * t;
    if (d < best || (d == best && j < bi)) { best = d; bi = j; }
  }
  if (lane == 0) idx[r] = bi;
}

extern "C" void kernel_launch(void* const* d_in, const int* in_sizes, int n_in,
                              void* d_out, int out_size, void* d_ws, size_t ws_size,
                              hipStream_t stream) {
  const float* x   = (const float*)d_in[0];
  const float* W1  = (const float*)d_in[1];
  const float* b1  = (const float*)d_in[2];
  const float* W2  = (const float*)d_in[3];
  const float* b2  = (const float*)d_in[4];
  const float* W3  = (const float*)d_in[5];
  const float* b3  = (const float*)d_in[6];
  const float* W4  = (const float*)d_in[7];
  const float* b4  = (const float*)d_in[8];
  const float* emb = (const float*)d_in[9];
  float* out = (float*)d_out;

  const int BZ = 16384, IN = 1024, H = 400, Hp = 512, D = 256, NE = 2048;

  char* ws = (char*)d_ws;
  size_t off = 0;
  auto alloc = [&](size_t bytes) {
    void* p = ws + off;
    off += (bytes + 255) & ~(size_t)255;
    return p;
  };
  unsigned short* w1h = (unsigned short*)alloc((size_t)Hp * IN * 2);
  unsigned short* w1m = (unsigned short*)alloc((size_t)Hp * IN * 2);
  unsigned short* w2h = (unsigned short*)alloc((size_t)D * Hp * 2);
  unsigned short* w2m = (unsigned short*)alloc((size_t)D * Hp * 2);
  unsigned short* w3h = (unsigned short*)alloc((size_t)Hp * D * 2);
  unsigned short* w3m = (unsigned short*)alloc((size_t)Hp * D * 2);
  unsigned short* w4h = (unsigned short*)alloc((size_t)IN * Hp * 2);
  unsigned short* w4m = (unsigned short*)alloc((size_t)IN * Hp * 2);
  unsigned short* eh  = (unsigned short*)alloc((size_t)NE * D * 2);
  unsigned short* em  = (unsigned short*)alloc((size_t)NE * D * 2);
  float* enorm = (float*)alloc((size_t)NE * 4);
  float* h1    = (float*)alloc((size_t)BZ * Hp * 4);
  float* z_e   = (float*)alloc((size_t)BZ * D * 4);
  float* h3    = (float*)alloc((size_t)BZ * Hp * 4);
  int*   pidx  = (int*)alloc((size_t)(NE / BN) * BZ * 2 * 4);
  int*   idx   = (int*)alloc((size_t)BZ * 4);

  // weight/codebook conversion + norms
  conv_pad<<<dim3((Hp * IN + 255) / 256), dim3(256), 0, stream>>>(W1, w1h, w1m, H, IN, Hp, IN);
  conv_pad<<<dim3((D * Hp + 255) / 256), dim3(256), 0, stream>>>(W2, w2h, w2m, D, H, D, Hp);
  conv_pad<<<dim3((Hp * D + 255) / 256), dim3(256), 0, stream>>>(W3, w3h, w3m, H, D, Hp, D);
  conv_pad<<<dim3((IN * Hp + 255) / 256), dim3(256), 0, stream>>>(W4, w4h, w4m, IN, H, IN, Hp);
  conv_pad<<<dim3((NE * D + 255) / 256), dim3(256), 0, stream>>>(emb, eh, em, NE, D, NE, D);
  emb_norm<<<dim3(NE * 64 / 256), dim3(256), 0, stream>>>(emb, enorm);

  // h1 = relu(x @ W1^T + b1)  -> [BZ][512] (cols 400.. are 0)
  mfma_gemm<EPI_RELU, false><<<dim3(Hp / BN, BZ / BM), dim3(256), 0, stream>>>(
      x, w1h, w1m, b1, h1, nullptr, nullptr, nullptr, BZ, Hp, IN, H);
  // z_e = h1 @ W2^T + b2  -> [BZ][256]
  mfma_gemm<EPI_NONE, false><<<dim3(D / BN, BZ / BM), dim3(256), 0, stream>>>(
      h1, w2h, w2m, b2, z_e, nullptr, nullptr, nullptr, BZ, D, Hp, D);
  // dist candidates: top-2 per 128-col chunk
  mfma_gemm<EPI_DIST, false><<<dim3(NE / BN, BZ / BM), dim3(256), 0, stream>>>(
      z_e, eh, em, nullptr, nullptr, nullptr, enorm, pidx, BZ, NE, D, NE);
  // exact fp32 rescore -> idx
  rescore<<<dim3(BZ / 4), dim3(256), 0, stream>>>(z_e, emb, enorm, pidx, idx, BZ);
  // h3 = relu(emb[idx] @ W3^T + b3) -> [BZ][512]
  mfma_gemm<EPI_RELU, true><<<dim3(Hp / BN, BZ / BM), dim3(256), 0, stream>>>(
      emb, w3h, w3m, b3, h3, idx, nullptr, nullptr, BZ, Hp, D, H);
  // out = sigmoid(h3 @ W4^T + b4) -> [BZ][1024]
  mfma_gemm<EPI_SIGMOID, false><<<dim3(IN / BN, BZ / BM), dim3(256), 0, stream>>>(
      h3, w4h, w4m, b4, out, nullptr, nullptr, nullptr, BZ, IN, Hp, IN);
}

// Round 3
// 409.202 us; speedup vs baseline: 2.7569x; 1.7486x over previous
//
#include <hip/hip_runtime.h>
#include <math.h>
#include <float.h>

// VQVAE forward, MI355X. Round 3: bf16x3 MFMA everywhere; dist restructured to
// 512 blocks with branchless packed-key top-3 (merge once per block); activations
// pre-split to bf16 hi/mid between GEMMs; exact fp32 rescore of 12 candidates.

typedef __attribute__((ext_vector_type(8))) short short8;      // MFMA A/B frag
typedef __attribute__((ext_vector_type(4))) float floatx4;     // MFMA C/D frag
typedef __attribute__((ext_vector_type(4))) unsigned short ushort4v;
typedef __attribute__((ext_vector_type(8))) unsigned short ushort8v;

__device__ __forceinline__ unsigned short f2bf(float f) {
  union { float f; unsigned u; } v; v.f = f;
  unsigned u = v.u;
  return (unsigned short)((u + 0x7FFFu + ((u >> 16) & 1u)) >> 16);
}
__device__ __forceinline__ float bf2f(unsigned short s) {
  union { unsigned u; float f; } v; v.u = ((unsigned)s) << 16;
  return v.f;
}

// monotone float->uint map, then pack col (0..2047) into low 11 bits.
// key ordering == (distance, col) lexicographic => first-occurrence argmin ties.
__device__ __forceinline__ unsigned packkey(float d, int c) {
  unsigned b = __float_as_uint(d);
  b = (b & 0x80000000u) ? ~b : (b | 0x80000000u);
  return (b & 0xFFFFF800u) | (unsigned)c;
}
// branchless sorted-top3 insert (v1<=v2<=v3)
__device__ __forceinline__ void ins3(unsigned k, unsigned& v1, unsigned& v2,
                                     unsigned& v3) {
  unsigned t1 = min(v1, k), c1 = max(v1, k);
  unsigned t2 = min(v2, c1), c2 = max(v2, c1);
  v1 = t1; v2 = t2; v3 = min(v3, c2);
}

// fp32 [R][C] -> zero-padded bf16 hi/mid [Rp][Cp]
__global__ __launch_bounds__(256) void conv_pad(
    const float* __restrict__ src, unsigned short* __restrict__ hi,
    unsigned short* __restrict__ mid, int R, int C, int Rp, int Cp) {
  int t = blockIdx.x * 256 + threadIdx.x;
  if (t >= Rp * Cp) return;
  int r = t / Cp, c = t - r * Cp;
  float v = (r < R && c < C) ? src[(long)r * C + c] : 0.f;
  unsigned short h = f2bf(v);
  hi[t] = h;
  mid[t] = f2bf(v - bf2f(h));
}

__global__ __launch_bounds__(256) void emb_norm(const float* __restrict__ emb,
                                                float* __restrict__ enorm) {
  const int gtid = blockIdx.x * 256 + threadIdx.x;
  const int j = gtid >> 6;
  const int lane = threadIdx.x & 63;
  float4 v = *(const float4*)(emb + (long)j * 256 + (lane << 2));
  float s = v.x * v.x + v.y * v.y + v.z * v.z + v.w * v.w;
#pragma unroll
  for (int off = 1; off < 64; off <<= 1) s += __shfl_xor(s, off, 64);
  if (lane == 0) enorm[j] = s;
}

#define BM 128
#define BN 128
#define BK 32
#define LDK 40

enum { EPI_NONE = 0, EPI_RELU = 1, EPI_SIGMOID = 2 };

// C = epi(A @ (Bhi+Bmid)^T + bias). A either fp32 (converted in staging) or
// pre-split hi/mid (ASPLIT). Output fp32 (Cf) or split hi/mid (OSPLIT).
template <int EPI, bool INDIRECT, bool ASPLIT, bool OSPLIT>
__global__ __launch_bounds__(256, 2) void mfma_gemm(
    const float* __restrict__ Af, const unsigned short* __restrict__ Ahg,
    const unsigned short* __restrict__ Amg, const unsigned short* __restrict__ Bhi,
    const unsigned short* __restrict__ Bmid, const float* __restrict__ bias,
    float* __restrict__ Cf, unsigned short* __restrict__ Ohi,
    unsigned short* __restrict__ Omid, const int* __restrict__ aidx,
    int M, int N, int K, int Nreal) {
  __shared__ unsigned short Ah[BM][LDK], Am[BM][LDK];
  __shared__ unsigned short Bh[BN][LDK], Bm[BN][LDK];
  __shared__ int idxs[BM];

  const int tid = threadIdx.x;
  const int lane = tid & 63;
  const int wave = tid >> 6;
  const int wm = wave >> 1, wn = wave & 1;
  const int row0 = blockIdx.y * BM, col0 = blockIdx.x * BN;

  if (INDIRECT) {
    if (tid < BM) idxs[tid] = aidx[row0 + tid];
    __syncthreads();
  }

  const float* aRowF[4];
  const unsigned short* aRowH[2];
  const unsigned short* aRowM[2];
  if (ASPLIT) {
#pragma unroll
    for (int i = 0; i < 2; i++) {
      int r = i * 64 + (tid >> 2);
      long ar = INDIRECT ? (long)idxs[r] : (long)(row0 + r);
      aRowH[i] = Ahg + ar * K + (tid & 3) * 8;
      aRowM[i] = Amg + ar * K + (tid & 3) * 8;
    }
  } else {
#pragma unroll
    for (int i = 0; i < 4; i++) {
      int r = i * 32 + (tid >> 3);
      long ar = INDIRECT ? (long)idxs[r] : (long)(row0 + r);
      aRowF[i] = Af + ar * K + (tid & 7) * 4;
    }
  }
  const unsigned short* bRowH[2];
  const unsigned short* bRowM[2];
#pragma unroll
  for (int i = 0; i < 2; i++) {
    int r = col0 + i * 64 + (tid >> 2);
    bRowH[i] = Bhi + (long)r * K + (tid & 3) * 8;
    bRowM[i] = Bmid + (long)r * K + (tid & 3) * 8;
  }

  floatx4 acc[4][4];
#pragma unroll
  for (int i = 0; i < 4; i++)
#pragma unroll
    for (int j = 0; j < 4; j++) acc[i][j] = (floatx4)0.f;

  for (int k0 = 0; k0 < K; k0 += BK) {
    float4 areg[4];
    ushort8v ah_reg[2], am_reg[2], bh_reg[2], bm_reg[2];
    if (ASPLIT) {
#pragma unroll
      for (int i = 0; i < 2; i++) {
        ah_reg[i] = *(const ushort8v*)(aRowH[i] + k0);
        am_reg[i] = *(const ushort8v*)(aRowM[i] + k0);
      }
    } else {
#pragma unroll
      for (int i = 0; i < 4; i++) areg[i] = *(const float4*)(aRowF[i] + k0);
    }
#pragma unroll
    for (int i = 0; i < 2; i++) {
      bh_reg[i] = *(const ushort8v*)(bRowH[i] + k0);
      bm_reg[i] = *(const ushort8v*)(bRowM[i] + k0);
    }
    __syncthreads();
    if (ASPLIT) {
#pragma unroll
      for (int i = 0; i < 2; i++) {
        int r = i * 64 + (tid >> 2), q8 = (tid & 3) * 8;
        *(ushort8v*)&Ah[r][q8] = ah_reg[i];
        *(ushort8v*)&Am[r][q8] = am_reg[i];
      }
    } else {
#pragma unroll
      for (int i = 0; i < 4; i++) {
        int r = i * 32 + (tid >> 3), q4 = (tid & 7) * 4;
        ushort4v h, m;
        h.x = f2bf(areg[i].x); m.x = f2bf(areg[i].x - bf2f(h.x));
        h.y = f2bf(areg[i].y); m.y = f2bf(areg[i].y - bf2f(h.y));
        h.z = f2bf(areg[i].z); m.z = f2bf(areg[i].z - bf2f(h.z));
        h.w = f2bf(areg[i].w); m.w = f2bf(areg[i].w - bf2f(h.w));
        *(ushort4v*)&Ah[r][q4] = h;
        *(ushort4v*)&Am[r][q4] = m;
      }
    }
#pragma unroll
    for (int i = 0; i < 2; i++) {
      int r = i * 64 + (tid >> 2), q8 = (tid & 3) * 8;
      *(ushort8v*)&Bh[r][q8] = bh_reg[i];
      *(ushort8v*)&Bm[r][q8] = bm_reg[i];
    }
    __syncthreads();

    short8 ah[4], am[4];
#pragma unroll
    for (int tm = 0; tm < 4; tm++) {
      const int rr = wm * 64 + tm * 16 + (lane & 15);
      const int kk = (lane >> 4) * 8;
      ah[tm] = *(const short8*)&Ah[rr][kk];
      am[tm] = *(const short8*)&Am[rr][kk];
    }
#pragma unroll
    for (int tn = 0; tn < 4; tn++) {
      const int rr = wn * 64 + tn * 16 + (lane & 15);
      const int kk = (lane >> 4) * 8;
      short8 bh = *(const short8*)&Bh[rr][kk];
      short8 bm = *(const short8*)&Bm[rr][kk];
#pragma unroll
      for (int tm = 0; tm < 4; tm++) {
        acc[tm][tn] = __builtin_amdgcn_mfma_f32_16x16x32_bf16(ah[tm], bh, acc[tm][tn], 0, 0, 0);
        acc[tm][tn] = __builtin_amdgcn_mfma_f32_16x16x32_bf16(ah[tm], bm, acc[tm][tn], 0, 0, 0);
        acc[tm][tn] = __builtin_amdgcn_mfma_f32_16x16x32_bf16(am[tm], bh, acc[tm][tn], 0, 0, 0);
      }
    }
  }

  const int qd = lane >> 4, ln = lane & 15;
#pragma unroll
  for (int tn = 0; tn < 4; tn++) {
    const int c = col0 + wn * 64 + tn * 16 + ln;
    const float bb = (c < Nreal) ? bias[c] : 0.f;
#pragma unroll
    for (int tm = 0; tm < 4; tm++) {
#pragma unroll
      for (int reg = 0; reg < 4; reg++) {
        const int r = row0 + wm * 64 + tm * 16 + qd * 4 + reg;
        float v = acc[tm][tn][reg] + bb;
        if (EPI == EPI_RELU) v = fmaxf(v, 0.f);
        if (EPI == EPI_SIGMOID) v = 1.f / (1.f + __expf(-v));
        if (OSPLIT) {
          unsigned short h = f2bf(v);
          Ohi[(long)r * N + c] = h;
          Omid[(long)r * N + c] = f2bf(v - bf2f(h));
        } else {
          Cf[(long)r * N + c] = v;
        }
      }
    }
  }
}

// dist candidates: grid (4, M/128). Block sweeps 512 cols in 4 chunks of 128,
// maintaining branchless per-lane packed-key top-3; one cross-lane merge at end.
__global__ __launch_bounds__(256, 2) void dist_topk(
    const float* __restrict__ Z, const unsigned short* __restrict__ Eh,
    const unsigned short* __restrict__ Em, const float* __restrict__ enorm,
    int* __restrict__ pidx, int M) {
  const int K = 256;
  __shared__ unsigned short Ah[BM][LDK], Am[BM][LDK];
  __shared__ unsigned short Bh[BN][LDK], Bm[BN][LDK];
  __shared__ unsigned r1s[2][BM], r2s[2][BM], r3s[2][BM];

  const int tid = threadIdx.x;
  const int lane = tid & 63;
  const int wave = tid >> 6;
  const int wm = wave >> 1, wn = wave & 1;
  const int row0 = blockIdx.y * BM;
  const int col_base = blockIdx.x * 512;

  const float* aRowF[4];
#pragma unroll
  for (int i = 0; i < 4; i++)
    aRowF[i] = Z + (long)(row0 + i * 32 + (tid >> 3)) * K + (tid & 7) * 4;

  unsigned k1[16], k2[16], k3[16];
#pragma unroll
  for (int s = 0; s < 16; s++) { k1[s] = 0xFFFFFFFFu; k2[s] = 0xFFFFFFFFu; k3[s] = 0xFFFFFFFFu; }

  for (int ch = 0; ch < 4; ch++) {
    const int col0 = col_base + ch * 128;
    floatx4 acc[4][4];
#pragma unroll
    for (int i = 0; i < 4; i++)
#pragma unroll
      for (int j = 0; j < 4; j++) acc[i][j] = (floatx4)0.f;

    for (int k0 = 0; k0 < K; k0 += BK) {
      float4 areg[4];
      ushort8v bh_reg[2], bm_reg[2];
#pragma unroll
      for (int i = 0; i < 4; i++) areg[i] = *(const float4*)(aRowF[i] + k0);
#pragma unroll
      for (int i = 0; i < 2; i++) {
        long r = col0 + i * 64 + (tid >> 2);
        bh_reg[i] = *(const ushort8v*)(Eh + r * K + (tid & 3) * 8 + k0);
        bm_reg[i] = *(const ushort8v*)(Em + r * K + (tid & 3) * 8 + k0);
      }
      __syncthreads();
#pragma unroll
      for (int i = 0; i < 4; i++) {
        int r = i * 32 + (tid >> 3), q4 = (tid & 7) * 4;
        ushort4v h, m;
        h.x = f2bf(areg[i].x); m.x = f2bf(areg[i].x - bf2f(h.x));
        h.y = f2bf(areg[i].y); m.y = f2bf(areg[i].y - bf2f(h.y));
        h.z = f2bf(areg[i].z); m.z = f2bf(areg[i].z - bf2f(h.z));
        h.w = f2bf(areg[i].w); m.w = f2bf(areg[i].w - bf2f(h.w));
        *(ushort4v*)&Ah[r][q4] = h;
        *(ushort4v*)&Am[r][q4] = m;
      }
#pragma unroll
      for (int i = 0; i < 2; i++) {
        int r = i * 64 + (tid >> 2), q8 = (tid & 3) * 8;
        *(ushort8v*)&Bh[r][q8] = bh_reg[i];
        *(ushort8v*)&Bm[r][q8] = bm_reg[i];
      }
      __syncthreads();

      short8 ah[4], am[4];
#pragma unroll
      for (int tm = 0; tm < 4; tm++) {
        const int rr = wm * 64 + tm * 16 + (lane & 15);
        const int kk = (lane >> 4) * 8;
        ah[tm] = *(const short8*)&Ah[rr][kk];
        am[tm] = *(const short8*)&Am[rr][kk];
      }
#pragma unroll
      for (int tn = 0; tn < 4; tn++) {
        const int rr = wn * 64 + tn * 16 + (lane & 15);
        const int kk = (lane >> 4) * 8;
        short8 bh = *(const short8*)&Bh[rr][kk];
        short8 bm = *(const short8*)&Bm[rr][kk];
#pragma unroll
        for (int tm = 0; tm < 4; tm++) {
          acc[tm][tn] = __builtin_amdgcn_mfma_f32_16x16x32_bf16(ah[tm], bh, acc[tm][tn], 0, 0, 0);
          acc[tm][tn] = __builtin_amdgcn_mfma_f32_16x16x32_bf16(ah[tm], bm, acc[tm][tn], 0, 0, 0);
          acc[tm][tn] = __builtin_amdgcn_mfma_f32_16x16x32_bf16(am[tm], bh, acc[tm][tn], 0, 0, 0);
        }
      }
    }

    // branchless per-lane inserts (no cross-lane traffic per chunk)
#pragma unroll
    for (int tn = 0; tn < 4; tn++) {
      const int c = col0 + wn * 64 + tn * 16 + (lane & 15);
      const float en = enorm[c];
#pragma unroll
      for (int tm = 0; tm < 4; tm++)
#pragma unroll
        for (int reg = 0; reg < 4; reg++) {
          float d = en - 2.f * acc[tm][tn][reg];
          const int s = tm * 4 + reg;
          ins3(packkey(d, c), k1[s], k2[s], k3[s]);
        }
    }
  }

  // cross-lane merge within 16-lane groups (once per block)
#pragma unroll
  for (int s = 0; s < 16; s++) {
#pragma unroll
    for (int off = 1; off < 16; off <<= 1) {
      unsigned o1 = __shfl_xor(k1[s], off, 64);
      unsigned o2 = __shfl_xor(k2[s], off, 64);
      unsigned o3 = __shfl_xor(k3[s], off, 64);
      ins3(o1, k1[s], k2[s], k3[s]);
      ins3(o2, k1[s], k2[s], k3[s]);
      ins3(o3, k1[s], k2[s], k3[s]);
    }
  }
  if ((lane & 15) == 0) {
#pragma unroll
    for (int s = 0; s < 16; s++) {
      int rl = wm * 64 + (s >> 2) * 16 + (lane >> 4) * 4 + (s & 3);
      r1s[wn][rl] = k1[s]; r2s[wn][rl] = k2[s]; r3s[wn][rl] = k3[s];
    }
  }
  __syncthreads();
  if (tid < BM) {
    unsigned v1 = r1s[0][tid], v2 = r2s[0][tid], v3 = r3s[0][tid];
    ins3(r1s[1][tid], v1, v2, v3);
    ins3(r2s[1][tid], v1, v2, v3);
    ins3(r3s[1][tid], v1, v2, v3);
    const long base = ((long)blockIdx.x * M + (row0 + tid)) * 4;
    pidx[base + 0] = (int)(v1 & 0x7FFu);
    pidx[base + 1] = (int)(v2 & 0x7FFu);
    pidx[base + 2] = (int)(v3 & 0x7FFu);
  }
}

// exact fp32 rescore of 12 candidates/row; one wave per row
__global__ __launch_bounds__(256) void rescore(
    const float* __restrict__ z, const float* __restrict__ emb,
    const float* __restrict__ enorm, const int* __restrict__ pidx,
    int* __restrict__ idx, int M) {
  const int wave = threadIdx.x >> 6, lane = threadIdx.x & 63;
  const int r = blockIdx.x * 4 + wave;
  float4 zv = *(const float4*)(z + (long)r * 256 + lane * 4);
  float best = FLT_MAX;
  int bi = 0x7fffffff;
#pragma unroll
  for (int g = 0; g < 4; g++) {
#pragma unroll
    for (int s = 0; s < 3; s++) {
      const int j = pidx[((long)g * M + r) * 4 + s];
      float4 ev = *(const float4*)(emb + (long)j * 256 + lane * 4);
      float t = zv.x * ev.x + zv.y * ev.y + zv.z * ev.z + zv.w * ev.w;
#pragma unroll
      for (int off = 1; off < 64; off <<= 1) t += __shfl_xor(t, off, 64);
      const float d = enorm[j] - 2.f * t;
      if (d < best || (d == best && j < bi)) { best = d; bi = j; }
    }
  }
  if (lane == 0) idx[r] = bi;
}

extern "C" void kernel_launch(void* const* d_in, const int* in_sizes, int n_in,
                              void* d_out, int out_size, void* d_ws, size_t ws_size,
                              hipStream_t stream) {
  const float* x   = (const float*)d_in[0];
  const float* W1  = (const float*)d_in[1];
  const float* b1  = (const float*)d_in[2];
  const float* W2  = (const float*)d_in[3];
  const float* b2  = (const float*)d_in[4];
  const float* W3  = (const float*)d_in[5];
  const float* b3  = (const float*)d_in[6];
  const float* W4  = (const float*)d_in[7];
  const float* b4  = (const float*)d_in[8];
  const float* emb = (const float*)d_in[9];
  float* out = (float*)d_out;

  const int BZ = 16384, IN = 1024, H = 400, Hp = 512, D = 256, NE = 2048;

  char* ws = (char*)d_ws;
  size_t off = 0;
  auto alloc = [&](size_t bytes) {
    void* p = ws + off;
    off += (bytes + 255) & ~(size_t)255;
    return p;
  };
  unsigned short* w1h = (unsigned short*)alloc((size_t)Hp * IN * 2);
  unsigned short* w1m = (unsigned short*)alloc((size_t)Hp * IN * 2);
  unsigned short* w2h = (unsigned short*)alloc((size_t)D * Hp * 2);
  unsigned short* w2m = (unsigned short*)alloc((size_t)D * Hp * 2);
  unsigned short* w3h = (unsigned short*)alloc((size_t)Hp * D * 2);
  unsigned short* w3m = (unsigned short*)alloc((size_t)Hp * D * 2);
  unsigned short* w4h = (unsigned short*)alloc((size_t)IN * Hp * 2);
  unsigned short* w4m = (unsigned short*)alloc((size_t)IN * Hp * 2);
  unsigned short* eh  = (unsigned short*)alloc((size_t)NE * D * 2);
  unsigned short* em  = (unsigned short*)alloc((size_t)NE * D * 2);
  float* enorm = (float*)alloc((size_t)NE * 4);
  unsigned short* h1h = (unsigned short*)alloc((size_t)BZ * Hp * 2);
  unsigned short* h1m = (unsigned short*)alloc((size_t)BZ * Hp * 2);
  float* z_e   = (float*)alloc((size_t)BZ * D * 4);
  unsigned short* h3h = (unsigned short*)alloc((size_t)BZ * Hp * 2);
  unsigned short* h3m = (unsigned short*)alloc((size_t)BZ * Hp * 2);
  int*   pidx  = (int*)alloc((size_t)4 * BZ * 4 * 4);
  int*   idx   = (int*)alloc((size_t)BZ * 4);

  conv_pad<<<dim3((Hp * IN + 255) / 256), dim3(256), 0, stream>>>(W1, w1h, w1m, H, IN, Hp, IN);
  conv_pad<<<dim3((D * Hp + 255) / 256), dim3(256), 0, stream>>>(W2, w2h, w2m, D, H, D, Hp);
  conv_pad<<<dim3((Hp * D + 255) / 256), dim3(256), 0, stream>>>(W3, w3h, w3m, H, D, Hp, D);
  conv_pad<<<dim3((IN * Hp + 255) / 256), dim3(256), 0, stream>>>(W4, w4h, w4m, IN, H, IN, Hp);
  conv_pad<<<dim3((NE * D + 255) / 256), dim3(256), 0, stream>>>(emb, eh, em, NE, D, NE, D);
  emb_norm<<<dim3(NE * 64 / 256), dim3(256), 0, stream>>>(emb, enorm);

  // h1 = relu(x @ W1^T + b1) -> hi/mid [BZ][512]
  mfma_gemm<EPI_RELU, false, false, true><<<dim3(Hp / BN, BZ / BM), dim3(256), 0, stream>>>(
      x, nullptr, nullptr, w1h, w1m, b1, nullptr, h1h, h1m, nullptr, BZ, Hp, IN, H);
  // z_e = h1 @ W2^T + b2 -> fp32 [BZ][256]
  mfma_gemm<EPI_NONE, false, true, false><<<dim3(D / BN, BZ / BM), dim3(256), 0, stream>>>(
      nullptr, h1h, h1m, w2h, w2m, b2, z_e, nullptr, nullptr, nullptr, BZ, D, Hp, D);
  // dist candidates: top-3 per 512-col group
  dist_topk<<<dim3(4, BZ / BM), dim3(256), 0, stream>>>(z_e, eh, em, enorm, pidx, BZ);
  // exact fp32 rescore -> idx
  rescore<<<dim3(BZ / 4), dim3(256), 0, stream>>>(z_e, emb, enorm, pidx, idx, BZ);
  // h3 = relu(emb[idx] @ W3^T + b3) -> hi/mid [BZ][512]  (gathers pre-split eh/em)
  mfma_gemm<EPI_RELU, true, true, true><<<dim3(Hp / BN, BZ / BM), dim3(256), 0, stream>>>(
      nullptr, eh, em, w3h, w3m, b3, nullptr, h3h, h3m, idx, BZ, Hp, D, H);
  // out = sigmoid(h3 @ W4^T + b4) -> fp32 [BZ][1024]
  mfma_gemm<EPI_SIGMOID, false, true, false><<<dim3(IN / BN, BZ / BM), dim3(256), 0, stream>>>(
      nullptr, h3h, h3m, w4h, w4m, b4, out, nullptr, nullptr, nullptr, BZ, IN, Hp, IN);
}

// Round 4
// 403.924 us; speedup vs baseline: 2.7929x; 1.0131x over previous
//
#include <hip/hip_runtime.h>
#include <math.h>
#include <float.h>

// VQVAE forward, MI355X. Round 4: m97-style K-loops — global_load_lds width=16
// direct-to-LDS staging, unpadded LDS tiles, pre-split activations everywhere.
// bf16x3 (hi/mid) MFMA = fp32-grade precision at MFMA rate. dist: branchless
// packed-key top-3 per 512-col group + exact fp32 rescore of 12 candidates.

typedef __attribute__((ext_vector_type(8))) short short8;      // MFMA A/B frag
typedef __attribute__((ext_vector_type(4))) float floatx4;     // MFMA C/D frag
typedef __attribute__((ext_vector_type(4))) unsigned short ushort4v;

__device__ __forceinline__ unsigned short f2bf(float f) {
  union { float f; unsigned u; } v; v.f = f;
  unsigned u = v.u;
  return (unsigned short)((u + 0x7FFFu + ((u >> 16) & 1u)) >> 16);
}
__device__ __forceinline__ float bf2f(unsigned short s) {
  union { unsigned u; float f; } v; v.u = ((unsigned)s) << 16;
  return v.f;
}

// async global->LDS, 16B per lane; LDS dest is wave-uniform base + lane*16
__device__ __forceinline__ void glds16(const void* g, void* l) {
  __builtin_amdgcn_global_load_lds(
      (const __attribute__((address_space(1))) unsigned int*)g,
      (__attribute__((address_space(3))) unsigned int*)l, 16, 0, 0);
}

// monotone float->uint map; col (0..2047) in low 11 bits => (dist, col) lexicographic
__device__ __forceinline__ unsigned packkey(float d, int c) {
  unsigned b = __float_as_uint(d);
  b = (b & 0x80000000u) ? ~b : (b | 0x80000000u);
  return (b & 0xFFFFF800u) | (unsigned)c;
}
__device__ __forceinline__ void ins3(unsigned k, unsigned& v1, unsigned& v2,
                                     unsigned& v3) {
  unsigned t1 = min(v1, k), c1 = max(v1, k);
  unsigned t2 = min(v2, c1), c2 = max(v2, c1);
  v1 = t1; v2 = t2; v3 = min(v3, c2);
}

__global__ __launch_bounds__(256) void conv_pad(
    const float* __restrict__ src, unsigned short* __restrict__ hi,
    unsigned short* __restrict__ mid, int R, int C, int Rp, int Cp) {
  int t = blockIdx.x * 256 + threadIdx.x;
  if (t >= Rp * Cp) return;
  int r = t / Cp, c = t - r * Cp;
  float v = (r < R && c < C) ? src[(long)r * C + c] : 0.f;
  unsigned short h = f2bf(v);
  hi[t] = h;
  mid[t] = f2bf(v - bf2f(h));
}

__global__ __launch_bounds__(256) void emb_norm(const float* __restrict__ emb,
                                                float* __restrict__ enorm) {
  const int gtid = blockIdx.x * 256 + threadIdx.x;
  const int j = gtid >> 6;
  const int lane = threadIdx.x & 63;
  float4 v = *(const float4*)(emb + (long)j * 256 + (lane << 2));
  float s = v.x * v.x + v.y * v.y + v.z * v.z + v.w * v.w;
#pragma unroll
  for (int off = 1; off < 64; off <<= 1) s += __shfl_xor(s, off, 64);
  if (lane == 0) enorm[j] = s;
}

#define BM 128
#define BN 128
#define BK 32

enum { EPI_NONE = 0, EPI_RELU = 1, EPI_SIGMOID = 2 };
// OMODE: 0 = fp32 out, 1 = hi/mid split out, 2 = both

template <int EPI, bool INDIRECT, bool ASPLIT, int OMODE>
__global__ __launch_bounds__(256, 3) void mfma_gemm(
    const float* __restrict__ Af, const unsigned short* __restrict__ Ahg,
    const unsigned short* __restrict__ Amg, const unsigned short* __restrict__ Bhi,
    const unsigned short* __restrict__ Bmid, const float* __restrict__ bias,
    float* __restrict__ Cf, unsigned short* __restrict__ Ohi,
    unsigned short* __restrict__ Omid, const int* __restrict__ aidx,
    int M, int N, int K, int Nreal) {
  __shared__ __align__(16) unsigned short Ah[BM][BK], Am[BM][BK];
  __shared__ __align__(16) unsigned short Bh[BN][BK], Bm[BN][BK];

  const int tid = threadIdx.x, lane = tid & 63, wave = tid >> 6;
  const int wm = wave >> 1, wn = wave & 1;
  const int row0 = blockIdx.y * BM, col0 = blockIdx.x * BN;
  const int kshort = (lane & 3) * 8;       // 16B granule within BK row
  unsigned short* AhL = &Ah[0][0];
  unsigned short* AmL = &Am[0][0];
  unsigned short* BhL = &Bh[0][0];
  unsigned short* BmL = &Bm[0][0];

  // staging sources (per-lane); slot = wave*2+j covers LDS rows slot*16..+15
  const unsigned short *aH[2], *aM2[2], *bH[2], *bM2[2];
  const float* aF[4];
  if (ASPLIT) {
#pragma unroll
    for (int j = 0; j < 2; j++) {
      const int rl = (wave * 2 + j) * 16 + (lane >> 2);
      const long ar = INDIRECT ? (long)aidx[row0 + rl] : (long)(row0 + rl);
      aH[j] = Ahg + ar * K + kshort;
      aM2[j] = Amg + ar * K + kshort;
    }
  } else {
#pragma unroll
    for (int i = 0; i < 4; i++)
      aF[i] = Af + (long)(row0 + i * 32 + (tid >> 3)) * K + (tid & 7) * 4;
  }
#pragma unroll
  for (int j = 0; j < 2; j++) {
    const int rl = (wave * 2 + j) * 16 + (lane >> 2);
    bH[j] = Bhi + (long)(col0 + rl) * K + kshort;
    bM2[j] = Bmid + (long)(col0 + rl) * K + kshort;
  }

  floatx4 acc[4][4];
#pragma unroll
  for (int i = 0; i < 4; i++)
#pragma unroll
    for (int j = 0; j < 4; j++) acc[i][j] = (floatx4)0.f;

  for (int k0 = 0; k0 < K; k0 += BK) {
    float4 areg[4];
    if (!ASPLIT) {
#pragma unroll
      for (int i = 0; i < 4; i++) areg[i] = *(const float4*)(aF[i] + k0);
    }
    __syncthreads();  // all waves done reading LDS (prev iter)
#pragma unroll
    for (int j = 0; j < 2; j++) {
      const int slot = wave * 2 + j;
      if (ASPLIT) {
        glds16(aH[j] + k0, AhL + slot * 512);
        glds16(aM2[j] + k0, AmL + slot * 512);
      }
      glds16(bH[j] + k0, BhL + slot * 512);
      glds16(bM2[j] + k0, BmL + slot * 512);
    }
    if (!ASPLIT) {
#pragma unroll
      for (int i = 0; i < 4; i++) {
        const int r = i * 32 + (tid >> 3), q4 = (tid & 7) * 4;
        ushort4v h, m;
        h.x = f2bf(areg[i].x); m.x = f2bf(areg[i].x - bf2f(h.x));
        h.y = f2bf(areg[i].y); m.y = f2bf(areg[i].y - bf2f(h.y));
        h.z = f2bf(areg[i].z); m.z = f2bf(areg[i].z - bf2f(h.z));
        h.w = f2bf(areg[i].w); m.w = f2bf(areg[i].w - bf2f(h.w));
        *(ushort4v*)&Ah[r][q4] = h;
        *(ushort4v*)&Am[r][q4] = m;
      }
    }
    __syncthreads();  // publish (compiler drains vmcnt+lgkmcnt)

    short8 ah[4], am[4];
#pragma unroll
    for (int tm = 0; tm < 4; tm++) {
      const int rr = wm * 64 + tm * 16 + (lane & 15);
      const int kk = (lane >> 4) * 8;
      ah[tm] = *(const short8*)&Ah[rr][kk];
      am[tm] = *(const short8*)&Am[rr][kk];
    }
#pragma unroll
    for (int tn = 0; tn < 4; tn++) {
      const int rr = wn * 64 + tn * 16 + (lane & 15);
      const int kk = (lane >> 4) * 8;
      short8 bh = *(const short8*)&Bh[rr][kk];
      short8 bm = *(const short8*)&Bm[rr][kk];
#pragma unroll
      for (int tm = 0; tm < 4; tm++) {
        acc[tm][tn] = __builtin_amdgcn_mfma_f32_16x16x32_bf16(ah[tm], bh, acc[tm][tn], 0, 0, 0);
        acc[tm][tn] = __builtin_amdgcn_mfma_f32_16x16x32_bf16(ah[tm], bm, acc[tm][tn], 0, 0, 0);
        acc[tm][tn] = __builtin_amdgcn_mfma_f32_16x16x32_bf16(am[tm], bh, acc[tm][tn], 0, 0, 0);
      }
    }
  }

  // C/D layout: col = lane&15, row = (lane>>4)*4 + reg
  const int qd = lane >> 4, ln = lane & 15;
#pragma unroll
  for (int tn = 0; tn < 4; tn++) {
    const int c = col0 + wn * 64 + tn * 16 + ln;
    const float bb = (c < Nreal) ? bias[c] : 0.f;
#pragma unroll
    for (int tm = 0; tm < 4; tm++) {
#pragma unroll
      for (int reg = 0; reg < 4; reg++) {
        const int r = row0 + wm * 64 + tm * 16 + qd * 4 + reg;
        float v = acc[tm][tn][reg] + bb;
        if (EPI == EPI_RELU) v = fmaxf(v, 0.f);
        if (EPI == EPI_SIGMOID) v = 1.f / (1.f + __expf(-v));
        if (OMODE == 0 || OMODE == 2) Cf[(long)r * N + c] = v;
        if (OMODE == 1 || OMODE == 2) {
          unsigned short h = f2bf(v);
          Ohi[(long)r * N + c] = h;
          Omid[(long)r * N + c] = f2bf(v - bf2f(h));
        }
      }
    }
  }
}

// dist candidates: grid (4, M/128); block sweeps 512 cols in 4 chunks of 128,
// branchless per-lane packed-key top-3, one cross-lane merge per block.
__global__ __launch_bounds__(256, 2) void dist_topk(
    const unsigned short* __restrict__ Zh, const unsigned short* __restrict__ Zm,
    const unsigned short* __restrict__ Eh, const unsigned short* __restrict__ Em,
    const float* __restrict__ enorm, int* __restrict__ pidx, int M) {
  const int K = 256;
  __shared__ __align__(16) unsigned short Ah[BM][BK], Am[BM][BK];
  __shared__ __align__(16) unsigned short Bh[BN][BK], Bm[BN][BK];
  __shared__ unsigned r1s[2][BM], r2s[2][BM], r3s[2][BM];

  const int tid = threadIdx.x, lane = tid & 63, wave = tid >> 6;
  const int wm = wave >> 1, wn = wave & 1;
  const int row0 = blockIdx.y * BM;
  const int col_base = blockIdx.x * 512;
  const int kshort = (lane & 3) * 8;
  unsigned short* AhL = &Ah[0][0];
  unsigned short* AmL = &Am[0][0];
  unsigned short* BhL = &Bh[0][0];
  unsigned short* BmL = &Bm[0][0];

  const unsigned short *aH[2], *aM2[2];
  int rlj[2];
#pragma unroll
  for (int j = 0; j < 2; j++) {
    rlj[j] = (wave * 2 + j) * 16 + (lane >> 2);
    aH[j] = Zh + (long)(row0 + rlj[j]) * K + kshort;
    aM2[j] = Zm + (long)(row0 + rlj[j]) * K + kshort;
  }

  unsigned k1[16], k2[16], k3[16];
#pragma unroll
  for (int s = 0; s < 16; s++) { k1[s] = 0xFFFFFFFFu; k2[s] = 0xFFFFFFFFu; k3[s] = 0xFFFFFFFFu; }

  for (int ch = 0; ch < 4; ch++) {
    const int col0 = col_base + ch * 128;
    floatx4 acc[4][4];
#pragma unroll
    for (int i = 0; i < 4; i++)
#pragma unroll
      for (int j = 0; j < 4; j++) acc[i][j] = (floatx4)0.f;

    for (int k0 = 0; k0 < K; k0 += BK) {
      __syncthreads();
#pragma unroll
      for (int j = 0; j < 2; j++) {
        const int slot = wave * 2 + j;
        glds16(aH[j] + k0, AhL + slot * 512);
        glds16(aM2[j] + k0, AmL + slot * 512);
        glds16(Eh + (long)(col0 + rlj[j]) * K + kshort + k0, BhL + slot * 512);
        glds16(Em + (long)(col0 + rlj[j]) * K + kshort + k0, BmL + slot * 512);
      }
      __syncthreads();

      short8 ah[4], am[4];
#pragma unroll
      for (int tm = 0; tm < 4; tm++) {
        const int rr = wm * 64 + tm * 16 + (lane & 15);
        const int kk = (lane >> 4) * 8;
        ah[tm] = *(const short8*)&Ah[rr][kk];
        am[tm] = *(const short8*)&Am[rr][kk];
      }
#pragma unroll
      for (int tn = 0; tn < 4; tn++) {
        const int rr = wn * 64 + tn * 16 + (lane & 15);
        const int kk = (lane >> 4) * 8;
        short8 bh = *(const short8*)&Bh[rr][kk];
        short8 bm = *(const short8*)&Bm[rr][kk];
#pragma unroll
        for (int tm = 0; tm < 4; tm++) {
          acc[tm][tn] = __builtin_amdgcn_mfma_f32_16x16x32_bf16(ah[tm], bh, acc[tm][tn], 0, 0, 0);
          acc[tm][tn] = __builtin_amdgcn_mfma_f32_16x16x32_bf16(ah[tm], bm, acc[tm][tn], 0, 0, 0);
          acc[tm][tn] = __builtin_amdgcn_mfma_f32_16x16x32_bf16(am[tm], bh, acc[tm][tn], 0, 0, 0);
        }
      }
    }

#pragma unroll
    for (int tn = 0; tn < 4; tn++) {
      const int c = col0 + wn * 64 + tn * 16 + (lane & 15);
      const float en = enorm[c];
#pragma unroll
      for (int tm = 0; tm < 4; tm++)
#pragma unroll
        for (int reg = 0; reg < 4; reg++) {
          float d = en - 2.f * acc[tm][tn][reg];
          const int s = tm * 4 + reg;
          ins3(packkey(d, c), k1[s], k2[s], k3[s]);
        }
    }
  }

#pragma unroll
  for (int s = 0; s < 16; s++) {
#pragma unroll
    for (int off = 1; off < 16; off <<= 1) {
      unsigned o1 = __shfl_xor(k1[s], off, 64);
      unsigned o2 = __shfl_xor(k2[s], off, 64);
      unsigned o3 = __shfl_xor(k3[s], off, 64);
      ins3(o1, k1[s], k2[s], k3[s]);
      ins3(o2, k1[s], k2[s], k3[s]);
      ins3(o3, k1[s], k2[s], k3[s]);
    }
  }
  if ((lane & 15) == 0) {
#pragma unroll
    for (int s = 0; s < 16; s++) {
      int rl = wm * 64 + (s >> 2) * 16 + (lane >> 4) * 4 + (s & 3);
      r1s[wn][rl] = k1[s]; r2s[wn][rl] = k2[s]; r3s[wn][rl] = k3[s];
    }
  }
  __syncthreads();
  if (tid < BM) {
    unsigned v1 = r1s[0][tid], v2 = r2s[0][tid], v3 = r3s[0][tid];
    ins3(r1s[1][tid], v1, v2, v3);
    ins3(r2s[1][tid], v1, v2, v3);
    ins3(r3s[1][tid], v1, v2, v3);
    const long base = ((long)blockIdx.x * M + (row0 + tid)) * 4;
    pidx[base + 0] = (int)(v1 & 0x7FFu);
    pidx[base + 1] = (int)(v2 & 0x7FFu);
    pidx[base + 2] = (int)(v3 & 0x7FFu);
  }
}

// exact fp32 rescore of 12 candidates/row; one wave per row
__global__ __launch_bounds__(256) void rescore(
    const float* __restrict__ z, const float* __restrict__ emb,
    const float* __restrict__ enorm, const int* __restrict__ pidx,
    int* __restrict__ idx, int M) {
  const int wave = threadIdx.x >> 6, lane = threadIdx.x & 63;
  const int r = blockIdx.x * 4 + wave;
  float4 zv = *(const float4*)(z + (long)r * 256 + lane * 4);
  float best = FLT_MAX;
  int bi = 0x7fffffff;
#pragma unroll
  for (int g = 0; g < 4; g++) {
#pragma unroll
    for (int s = 0; s < 3; s++) {
      const int j = pidx[((long)g * M + r) * 4 + s];
      float4 ev = *(const float4*)(emb + (long)j * 256 + lane * 4);
      float t = zv.x * ev.x + zv.y * ev.y + zv.z * ev.z + zv.w * ev.w;
#pragma unroll
      for (int off = 1; off < 64; off <<= 1) t += __shfl_xor(t, off, 64);
      const float d = enorm[j] - 2.f * t;
      if (d < best || (d == best && j < bi)) { best = d; bi = j; }
    }
  }
  if (lane == 0) idx[r] = bi;
}

extern "C" void kernel_launch(void* const* d_in, const int* in_sizes, int n_in,
                              void* d_out, int out_size, void* d_ws, size_t ws_size,
                              hipStream_t stream) {
  const float* x   = (const float*)d_in[0];
  const float* W1  = (const float*)d_in[1];
  const float* b1  = (const float*)d_in[2];
  const float* W2  = (const float*)d_in[3];
  const float* b2  = (const float*)d_in[4];
  const float* W3  = (const float*)d_in[5];
  const float* b3  = (const float*)d_in[6];
  const float* W4  = (const float*)d_in[7];
  const float* b4  = (const float*)d_in[8];
  const float* emb = (const float*)d_in[9];
  float* out = (float*)d_out;

  const int BZ = 16384, IN = 1024, H = 400, Hp = 512, D = 256, NE = 2048;

  char* ws = (char*)d_ws;
  size_t off = 0;
  auto alloc = [&](size_t bytes) {
    void* p = ws + off;
    off += (bytes + 255) & ~(size_t)255;
    return p;
  };
  unsigned short* w1h = (unsigned short*)alloc((size_t)Hp * IN * 2);
  unsigned short* w1m = (unsigned short*)alloc((size_t)Hp * IN * 2);
  unsigned short* w2h = (unsigned short*)alloc((size_t)D * Hp * 2);
  unsigned short* w2m = (unsigned short*)alloc((size_t)D * Hp * 2);
  unsigned short* w3h = (unsigned short*)alloc((size_t)Hp * D * 2);
  unsigned short* w3m = (unsigned short*)alloc((size_t)Hp * D * 2);
  unsigned short* w4h = (unsigned short*)alloc((size_t)IN * Hp * 2);
  unsigned short* w4m = (unsigned short*)alloc((size_t)IN * Hp * 2);
  unsigned short* eh  = (unsigned short*)alloc((size_t)NE * D * 2);
  unsigned short* em  = (unsigned short*)alloc((size_t)NE * D * 2);
  float* enorm = (float*)alloc((size_t)NE * 4);
  unsigned short* h1h = (unsigned short*)alloc((size_t)BZ * Hp * 2);  // 16MB
  unsigned short* h1m = (unsigned short*)alloc((size_t)BZ * Hp * 2);  // 16MB
  float* zf = (float*)alloc((size_t)BZ * D * 4);                       // 16MB
  unsigned short* zh = (unsigned short*)alloc((size_t)BZ * D * 2);     // 8MB
  unsigned short* zm = (unsigned short*)alloc((size_t)BZ * D * 2);     // 8MB (contig after zh)
  // aliases (lifetimes disjoint on the sequential stream):
  unsigned short* h3h = (unsigned short*)zf;   // zf dead after rescore
  unsigned short* h3m = zh;                    // zh+zm (16MB contig) dead after dist
  int* pidx = (int*)h1h;                       // h1 dead after GEMM2
  int* idx  = ((int*)h1h) + (size_t)4 * BZ * 4;

  conv_pad<<<dim3((Hp * IN + 255) / 256), dim3(256), 0, stream>>>(W1, w1h, w1m, H, IN, Hp, IN);
  conv_pad<<<dim3((D * Hp + 255) / 256), dim3(256), 0, stream>>>(W2, w2h, w2m, D, H, D, Hp);
  conv_pad<<<dim3((Hp * D + 255) / 256), dim3(256), 0, stream>>>(W3, w3h, w3m, H, D, Hp, D);
  conv_pad<<<dim3((IN * Hp + 255) / 256), dim3(256), 0, stream>>>(W4, w4h, w4m, IN, H, IN, Hp);
  conv_pad<<<dim3((NE * D + 255) / 256), dim3(256), 0, stream>>>(emb, eh, em, NE, D, NE, D);
  emb_norm<<<dim3(NE * 64 / 256), dim3(256), 0, stream>>>(emb, enorm);

  // h1 = relu(x @ W1^T + b1) -> hi/mid [BZ][512]
  mfma_gemm<EPI_RELU, false, false, 1><<<dim3(Hp / BN, BZ / BM), dim3(256), 0, stream>>>(
      x, nullptr, nullptr, w1h, w1m, b1, nullptr, h1h, h1m, nullptr, BZ, Hp, IN, H);
  // z_e = h1 @ W2^T + b2 -> fp32 + hi/mid [BZ][256]
  mfma_gemm<EPI_NONE, false, true, 2><<<dim3(D / BN, BZ / BM), dim3(256), 0, stream>>>(
      nullptr, h1h, h1m, w2h, w2m, b2, zf, zh, zm, nullptr, BZ, D, Hp, D);
  // dist candidates: top-3 per 512-col group
  dist_topk<<<dim3(4, BZ / BM), dim3(256), 0, stream>>>(zh, zm, eh, em, enorm, pidx, BZ);
  // exact fp32 rescore -> idx
  rescore<<<dim3(BZ / 4), dim3(256), 0, stream>>>(zf, emb, enorm, pidx, idx, BZ);
  // h3 = relu(emb[idx] @ W3^T + b3) -> hi/mid [BZ][512] (gathers pre-split eh/em)
  mfma_gemm<EPI_RELU, true, true, 1><<<dim3(Hp / BN, BZ / BM), dim3(256), 0, stream>>>(
      nullptr, eh, em, w3h, w3m, b3, nullptr, h3h, h3m, idx, BZ, Hp, D, H);
  // out = sigmoid(h3 @ W4^T + b4) -> fp32 [BZ][1024]
  mfma_gemm<EPI_SIGMOID, false, true, 0><<<dim3(IN / BN, BZ / BM), dim3(256), 0, stream>>>(
      nullptr, h3h, h3m, w4h, w4m, b4, out, nullptr, nullptr, nullptr, BZ, IN, Hp, IN);
}